// Round 4
// 6158.000 us; speedup vs baseline: 1.2299x; 1.2299x over previous
//
#include <hip/hip_runtime.h>
#include <stdint.h>

// MinGRU persistent kernel for MI355X (gfx950).  Round 6 = Round 5 re-run.
// (R5 bench died with "MI355X container failed twice" -- infra-level failure
// before pytest; no kernel result.  Source audited for container-lethal
// defects: none -- all indices bounded, all spin loops guarded (2^18), launch
// shapes match the R2 kernel that benched cleanly.  Resubmitting unchanged to
// keep the experiment clean.)
//
// B=128, T=1024, I=256, H=512.
// 8 clusters (16 batches) x 8 WGs (64 H-cols); 512 threads = 8 waves/WG.
// R5 post-mortem of R4: the XCD fast-path trial was UNSOUND -- non-sc1
// atomics on different XCDs keep per-L2 copies of the counter line, and
// eviction/refill traffic lets partial sums trickle through memory, so a
// cross-XCD cluster can spuriously pass the trial and then exchange h
// through non-coherent L2s (absmax 0.53).  Fast path withdrawn.
// R5/R6 = device-scope only, isolating the sound improvements over R2:
//   1. Single poller thread per WG on ONE per-cluster sum counter
//      (R2: 512 threads x 64 WGs polling 64 flag lines -> coherence-point
//      queueing inflates every RT in the step chain).
//      Sum-barrier soundness: staging at step t+2 requires sum >= 8(t+2),
//      which forces ALL WGs to have completed step t+1 -> slot-parity
//      reuse is race-free.
//   2. x prefetched one step ahead into registers (x-load latency drains
//      under the sync wait / h-MFMA instead of sitting on the serial path).
//   3. Split MFMA accumulator chain (acc/acc2) halves dependent depth.
// Publish / staging / poll ops are byte-for-byte R2's proven
// __hip_atomic_* (relaxed, agent scope) forms.

#define Bb 128
#define Tt 1024
#define Ii 256
#define Hh 512
#define HB_PAR (8 * 16 * 256)   // u32 words per parity slot
#define FLAGS_OFF (2 * HB_PAR)  // u32 offset of flag region in ws
#define NFLAG_W 256             // 8 clusters x 32-word (128B) padded ctr lines

typedef short short8 __attribute__((ext_vector_type(8)));
typedef float float4_ __attribute__((ext_vector_type(4)));
typedef unsigned int uint4_ __attribute__((ext_vector_type(4)));

__device__ __forceinline__ unsigned short f2bf(float f) {
  union { float f; uint32_t u; } v; v.f = f;
  uint32_t r = v.u + 0x7FFFu + ((v.u >> 16) & 1u);  // RNE
  return (unsigned short)(r >> 16);
}

__global__ void prep_kernel(uint32_t* ws) {
  int i = blockIdx.x * 256 + threadIdx.x;
  if (i < NFLAG_W) ws[FLAGS_OFF + i] = 0u;  // per-cluster step counters
}

__global__ __launch_bounds__(512, 2) void mingru_kernel(
    const float* __restrict__ x, const float* __restrict__ Wz,
    const float* __restrict__ bz, const float* __restrict__ Wh,
    const float* __restrict__ bh, float* __restrict__ out,
    uint32_t* __restrict__ hbuf) {
  const int bg = blockIdx.x & 7;    // cluster (batch group of 16)
  const int cs = blockIdx.x >> 3;   // this WG's column slice (64 H-cols)
  const int tid = threadIdx.x;
  const int wave = tid >> 6;
  const int lane = tid & 63;
  const int lm = lane & 15;
  const int quad = lane >> 4;
  const int is_h = (wave >> 2) & 1; // 0: z-gate (Wz), 1: h~ (Wh)
  const int tile = wave & 3;
  const int wcol = cs * 64 + tile * 16 + lm;
  const float* W = is_h ? Wh : Wz;

  uint32_t* ctrp = hbuf + FLAGS_OFF + (size_t)bg * 32;  // per-cluster sum counter

  // ---- one-time: load W fragments into registers (bf16) ----
  // B-frag (16x16x32): lane holds B[k = quad*8 + j][n = lane&15]
  short8 wx[8], wh[16];
#pragma unroll
  for (int s = 0; s < 8; ++s) {
    union { unsigned short e[8]; short8 v; } u;
#pragma unroll
    for (int j = 0; j < 8; ++j)
      u.e[j] = f2bf(W[(size_t)(s * 32 + quad * 8 + j) * Hh + wcol]);
    wx[s] = u.v;
  }
#pragma unroll
  for (int s = 0; s < 16; ++s) {
    union { unsigned short e[8]; short8 v; } u;
#pragma unroll
    for (int j = 0; j < 8; ++j)
      u.e[j] = f2bf(W[(size_t)(Ii + s * 32 + quad * 8 + j) * Hh + wcol]);
    wh[s] = u.v;
  }

  __shared__ uint32_t hs[16 * 260];  // staged h_{t-1} (bf16 pairs), padded rows
  __shared__ float S[2][16][66];     // pre-activation z / h~ tiles

  // ---- epilogue ownership: lane (m = tid>>5, cols ec,ec+1), fp32 h in regs ----
  const int em = tid >> 5;
  const int ec = (tid & 31) << 1;
  const int ecolg = cs * 64 + ec;
  const int eb = bg * 16 + em;
  const float bz0 = bz[ecolg], bz1 = bz[ecolg + 1];
  const float bh0 = bh[ecolg], bh1 = bh[ecolg + 1];
  float hp0 = 0.f, hp1 = 0.f;
  float* outp = out + (size_t)eb * (Tt * Hh) + ecolg;
  const uint32_t epair = (uint32_t)((bg * 16 + em) * 256 + (ecolg >> 1));

  // ---- x prefetch registers: one full step ahead ----
  const float* xlane = x + (size_t)(bg * 16 + lm) * (Tt * Ii) + quad * 8;
  float4_ xf[16];
#pragma unroll
  for (int s = 0; s < 8; ++s) {
    xf[2 * s] = *(const float4_*)(xlane + 32 * s);
    xf[2 * s + 1] = *(const float4_*)(xlane + 32 * s + 4);
  }

  for (int t = 0; t < Tt; ++t) {
    // ---- x-part MFMAs from prefetched registers ----
    float4_ acc = {0.f, 0.f, 0.f, 0.f};
    float4_ acc2 = {0.f, 0.f, 0.f, 0.f};
#pragma unroll
    for (int s = 0; s < 8; ++s) {
      float4_ a0 = xf[2 * s];
      float4_ a1 = xf[2 * s + 1];
      union { unsigned short e[8]; short8 v; } u;
      u.e[0] = f2bf(a0[0]); u.e[1] = f2bf(a0[1]);
      u.e[2] = f2bf(a0[2]); u.e[3] = f2bf(a0[3]);
      u.e[4] = f2bf(a1[0]); u.e[5] = f2bf(a1[1]);
      u.e[6] = f2bf(a1[2]); u.e[7] = f2bf(a1[3]);
      if (s & 1)
        acc2 = __builtin_amdgcn_mfma_f32_16x16x32_bf16(u.v, wx[s], acc2, 0, 0, 0);
      else
        acc = __builtin_amdgcn_mfma_f32_16x16x32_bf16(u.v, wx[s], acc, 0, 0, 0);
    }

    if (t > 0) {
      // ---- single-poller wait: tid0 spins on the cluster sum counter ----
      if (tid == 0) {
        const uint32_t tgt = 8u * (uint32_t)t;
        int spins = 0;
        while (__hip_atomic_load(ctrp, __ATOMIC_RELAXED,
                                 __HIP_MEMORY_SCOPE_AGENT) < tgt) {
          if (++spins > (1 << 18)) break;  // bounded: visible wrong answer, no hang
        }
      }
      __syncthreads();
      // ---- stage h_{t-1} (slot (t-1)&1): 4 u64 relaxed atomic loads/thread ----
      {
        unsigned long long* hq =
            (unsigned long long*)(hbuf + ((t - 1) & 1) * HB_PAR) + (size_t)bg * 2048;
#pragma unroll
        for (int k = 0; k < 4; ++k) {
          int g = tid + 512 * k;
          unsigned long long v = __hip_atomic_load(hq + g, __ATOMIC_RELAXED,
                                                   __HIP_MEMORY_SCOPE_AGENT);
          int m = g >> 7, c = g & 127;
          *(unsigned long long*)&hs[m * 260 + c * 2] = v;
        }
      }
      __syncthreads();
    }

    // ---- issue x prefetch for t+1 (drains under h-MFMA/epilogue) ----
    {
      const float* xp = xlane + (size_t)((t + 1 < Tt) ? t + 1 : t) * Ii;
#pragma unroll
      for (int s = 0; s < 8; ++s) {
        xf[2 * s] = *(const float4_*)(xp + 32 * s);
        xf[2 * s + 1] = *(const float4_*)(xp + 32 * s + 4);
      }
    }

    if (t > 0) {
      // ---- h-part MFMAs: A-frag = h[m = lane&15][k = 32s + quad*8 + j] ----
#pragma unroll
      for (int s = 0; s < 16; ++s) {
        uint4_ d = *(const uint4_*)&hs[lm * 260 + s * 16 + quad * 4];
        union { uint4_ q; short8 v; } u; u.q = d;
        if (s & 1)
          acc2 = __builtin_amdgcn_mfma_f32_16x16x32_bf16(u.v, wh[s], acc2, 0, 0, 0);
        else
          acc = __builtin_amdgcn_mfma_f32_16x16x32_bf16(u.v, wh[s], acc, 0, 0, 0);
      }
    }

    // ---- pair z / h~ tiles via LDS (C/D: row = quad*4+r, col = lane&15) ----
    S[is_h][quad * 4 + 0][tile * 16 + lm] = acc[0] + acc2[0];
    S[is_h][quad * 4 + 1][tile * 16 + lm] = acc[1] + acc2[1];
    S[is_h][quad * 4 + 2][tile * 16 + lm] = acc[2] + acc2[2];
    S[is_h][quad * 4 + 3][tile * 16 + lm] = acc[3] + acc2[3];
    __syncthreads();

    // ---- epilogue: gates in fp32, update register-resident h ----
    float sz0 = S[0][em][ec]     + bz0;
    float sz1 = S[0][em][ec + 1] + bz1;
    float sh0 = S[1][em][ec]     + bh0;
    float sh1 = S[1][em][ec + 1] + bh1;
    float z0 = 1.f / (1.f + __expf(-sz0));
    float z1 = 1.f / (1.f + __expf(-sz1));
    float g0 = 1.f - 2.f / (1.f + __expf(2.f * sh0));
    float g1 = 1.f - 2.f / (1.f + __expf(2.f * sh1));
    hp0 += z0 * (g0 - hp0);
    hp1 += z1 * (g1 - hp1);

    // ---- publish h_t to slot t&1 (relaxed agent store, R2-proven) ----
    uint32_t pk = (uint32_t)f2bf(hp0) | ((uint32_t)f2bf(hp1) << 16);
    __hip_atomic_store(hbuf + (t & 1) * HB_PAR + epair, pk,
                       __ATOMIC_RELAXED, __HIP_MEMORY_SCOPE_AGENT);
    // per-wave drain (store ACKed at coherence point), WG-wide rendezvous,
    // then ONE counter bump per WG.
    __builtin_amdgcn_s_waitcnt(0);
    __syncthreads();
    if (tid == 0)
      __hip_atomic_fetch_add(ctrp, 1u, __ATOMIC_RELAXED, __HIP_MEMORY_SCOPE_AGENT);

    // ---- output stores AFTER signal: off the inter-WG critical path ----
    float2 ov; ov.x = hp0; ov.y = hp1;
    *(float2*)(outp + (size_t)t * Hh) = ov;
    if (t == Tt - 1)
      *(float2*)(out + (size_t)Bb * Tt * Hh + (size_t)eb * Hh + ecolg) = ov;
  }
}

extern "C" void kernel_launch(void* const* d_in, const int* in_sizes, int n_in,
                              void* d_out, int out_size, void* d_ws, size_t ws_size,
                              hipStream_t stream) {
  const float* x  = (const float*)d_in[0];
  const float* Wz = (const float*)d_in[1];
  const float* bz = (const float*)d_in[2];
  const float* Wh = (const float*)d_in[3];
  const float* bh = (const float*)d_in[4];
  float* out = (float*)d_out;
  uint32_t* hbuf = (uint32_t*)d_ws;  // 2*HB_PAR u32 h-slots + 256-word flag region

  prep_kernel<<<dim3(1), dim3(256), 0, stream>>>(hbuf);
  mingru_kernel<<<dim3(64), dim3(512), 0, stream>>>(x, Wz, bz, Wh, bh, out, hbuf);
}

// Round 5
// 5019.869 us; speedup vs baseline: 1.5087x; 1.2267x over previous
//
#include <hip/hip_runtime.h>
#include <stdint.h>

// MinGRU persistent kernel for MI355X (gfx950).  Round 7.
// B=128, T=1024, I=256, H=512.
// 8 clusters (16 batches) x 8 WGs (64 H-cols); 512 threads = 8 waves/WG.
//
// R6 post-mortem: 5920us = 13.9k cyc/step; chain = ~4.5 serial device-scope
// RTs (publish-ACK, bump, poll-detect, staging-load) => RT ~ 2.5-3k cyc.
// R7: DATA-AS-SIGNAL. No flags, no counter, no publish ACK wait:
//   - 4-deep h slot rotation; consumers poll the data words against a
//     poison sentinel 0xFFFFFFFF (bf16 NaN|NaN -- impossible for finite h,
//     sigma/tanh-gated).  The staging load IS the poll.
//   - Producer: epilogue -> relaxed store -> done (fire and forget).
//   - Re-poison: each word's OWNER thread poisons slot (t+2)&3 at step t,
//     AFTER the hs __syncthreads.  Barrier proves: WG staged all 4096
//     cluster words => every producer thread published t-1 => every thread
//     passed its own t-1 staging barrier => nobody still reads (t+2)&3.
//     Owner-only re-poison => same-thread same-address => per-location
//     coherence orders poison(t) < data(t+2).  D=4 required (D=3 races a
//     straggler mid-consume).
//   - Stale reads impossible: write order old < poison < new per location;
//     sc0 sc1 polls are coherence-point serviced; each poll round's
//     vmcnt(0) drains own poison 2 full steps before consumers need it.
//     Worst case under doubt is "see poison -> retry", never silent-stale.
//   - Barriers per step: 4 -> 2.
// Kept from R6: single... (no pollers needed at all now), x register
// prefetch one step ahead, split MFMA accumulator chain.

#define Bb 128
#define Tt 1024
#define Ii 256
#define Hh 512
#define HB_PAR (8 * 16 * 256)   // 32768 u32 words per slot (clusters x batches x pairs)
#define NSLOT 4                 // 4-deep rotation (poison-timing proof needs >=4)
#define POISON 0xFFFFFFFFu      // bf16 NaN|NaN: unreachable for finite h

typedef short short8 __attribute__((ext_vector_type(8)));
typedef float float4_ __attribute__((ext_vector_type(4)));
typedef unsigned int uint4_ __attribute__((ext_vector_type(4)));

__device__ __forceinline__ unsigned short f2bf(float f) {
  union { float f; uint32_t u; } v; v.f = f;
  uint32_t r = v.u + 0x7FFFu + ((v.u >> 16) & 1u);  // RNE
  return (unsigned short)(r >> 16);
}

__global__ void prep_kernel(uint32_t* ws) {
  int i = blockIdx.x * 256 + threadIdx.x;  // 512 blocks x 256
  if (i < NSLOT * HB_PAR) ws[i] = POISON;
}

// fresh 32B read from the coherence point (bypasses L1/L2)
__device__ __forceinline__ void poll32(const uint32_t* p, uint4_& a, uint4_& b) {
  asm volatile(
      "global_load_dwordx4 %0, %2, off sc0 sc1\n\t"
      "global_load_dwordx4 %1, %2, off offset:16 sc0 sc1\n\t"
      "s_waitcnt vmcnt(0)"
      : "=&v"(a), "=&v"(b)
      : "v"(p)
      : "memory");
}

__global__ __launch_bounds__(512, 2) void mingru_kernel(
    const float* __restrict__ x, const float* __restrict__ Wz,
    const float* __restrict__ bz, const float* __restrict__ Wh,
    const float* __restrict__ bh, float* __restrict__ out,
    uint32_t* __restrict__ hbuf) {
  const int bg = blockIdx.x & 7;    // cluster (batch group of 16)
  const int cs = blockIdx.x >> 3;   // this WG's column slice (64 H-cols)
  const int tid = threadIdx.x;
  const int wave = tid >> 6;
  const int lane = tid & 63;
  const int lm = lane & 15;
  const int quad = lane >> 4;
  const int is_h = (wave >> 2) & 1; // 0: z-gate (Wz), 1: h~ (Wh)
  const int tile = wave & 3;
  const int wcol = cs * 64 + tile * 16 + lm;
  const float* W = is_h ? Wh : Wz;

  // ---- one-time: load W fragments into registers (bf16) ----
  // B-frag (16x16x32): lane holds B[k = quad*8 + j][n = lane&15]
  short8 wx[8], wh[16];
#pragma unroll
  for (int s = 0; s < 8; ++s) {
    union { unsigned short e[8]; short8 v; } u;
#pragma unroll
    for (int j = 0; j < 8; ++j)
      u.e[j] = f2bf(W[(size_t)(s * 32 + quad * 8 + j) * Hh + wcol]);
    wx[s] = u.v;
  }
#pragma unroll
  for (int s = 0; s < 16; ++s) {
    union { unsigned short e[8]; short8 v; } u;
#pragma unroll
    for (int j = 0; j < 8; ++j)
      u.e[j] = f2bf(W[(size_t)(Ii + s * 32 + quad * 8 + j) * Hh + wcol]);
    wh[s] = u.v;
  }

  __shared__ uint32_t hs[16 * 260];  // staged h_{t-1} (bf16 pairs), padded rows
  __shared__ float S[2][16][66];     // pre-activation z / h~ tiles

  // ---- epilogue ownership: lane (m = tid>>5, cols ec,ec+1), fp32 h in regs ----
  const int em = tid >> 5;
  const int ec = (tid & 31) << 1;
  const int ecolg = cs * 64 + ec;
  const int eb = bg * 16 + em;
  const float bz0 = bz[ecolg], bz1 = bz[ecolg + 1];
  const float bh0 = bh[ecolg], bh1 = bh[ecolg + 1];
  float hp0 = 0.f, hp1 = 0.f;
  float* outp = out + (size_t)eb * (Tt * Hh) + ecolg;
  const uint32_t epair = (uint32_t)((bg * 16 + em) * 256 + (ecolg >> 1));

  // ---- x prefetch registers: one full step ahead ----
  const float* xlane = x + (size_t)(bg * 16 + lm) * (Tt * Ii) + quad * 8;
  float4_ xf[16];
#pragma unroll
  for (int s = 0; s < 8; ++s) {
    xf[2 * s] = *(const float4_*)(xlane + 32 * s);
    xf[2 * s + 1] = *(const float4_*)(xlane + 32 * s + 4);
  }

  for (int t = 0; t < Tt; ++t) {
    // ---- x-part MFMAs from prefetched registers (fills the wait shadow) ----
    float4_ acc = {0.f, 0.f, 0.f, 0.f};
    float4_ acc2 = {0.f, 0.f, 0.f, 0.f};
#pragma unroll
    for (int s = 0; s < 8; ++s) {
      float4_ a0 = xf[2 * s];
      float4_ a1 = xf[2 * s + 1];
      union { unsigned short e[8]; short8 v; } u;
      u.e[0] = f2bf(a0[0]); u.e[1] = f2bf(a0[1]);
      u.e[2] = f2bf(a0[2]); u.e[3] = f2bf(a0[3]);
      u.e[4] = f2bf(a1[0]); u.e[5] = f2bf(a1[1]);
      u.e[6] = f2bf(a1[2]); u.e[7] = f2bf(a1[3]);
      if (s & 1)
        acc2 = __builtin_amdgcn_mfma_f32_16x16x32_bf16(u.v, wx[s], acc2, 0, 0, 0);
      else
        acc = __builtin_amdgcn_mfma_f32_16x16x32_bf16(u.v, wx[s], acc, 0, 0, 0);
    }

    if (t > 0) {
      // ---- poll-stage h_{t-1} from slot (t-1)&3: the load IS the signal ----
      {
        const uint32_t* pp =
            hbuf + (size_t)((t - 1) & 3) * HB_PAR + bg * 4096 + 8 * tid;
        uint4_ d0, d1;
        int rounds = 0;
        for (;;) {
          poll32(pp, d0, d1);
          int ok = (d0[0] != POISON) & (d0[1] != POISON) &
                   (d0[2] != POISON) & (d0[3] != POISON) &
                   (d1[0] != POISON) & (d1[1] != POISON) &
                   (d1[2] != POISON) & (d1[3] != POISON);
          if (ok || ++rounds > (1 << 12)) break;  // bounded: no hang, visible if wrong
        }
        const int m = tid >> 5;
        const int c0 = 8 * (tid & 31);
        *(uint4_*)&hs[m * 260 + c0] = d0;
        *(uint4_*)&hs[m * 260 + c0 + 4] = d1;
      }
      __syncthreads();
      // ---- owner re-poison of slot (t+2)&3 (safe: barrier above proves all
      //      cluster threads are past consuming that slot's old data) ----
      __hip_atomic_store(hbuf + (size_t)((t + 2) & 3) * HB_PAR + epair, POISON,
                         __ATOMIC_RELAXED, __HIP_MEMORY_SCOPE_AGENT);
    }

    // ---- issue x prefetch for t+1 (drains under h-MFMA/epilogue) ----
    {
      const float* xp = xlane + (size_t)((t + 1 < Tt) ? t + 1 : t) * Ii;
#pragma unroll
      for (int s = 0; s < 8; ++s) {
        xf[2 * s] = *(const float4_*)(xp + 32 * s);
        xf[2 * s + 1] = *(const float4_*)(xp + 32 * s + 4);
      }
    }

    if (t > 0) {
      // ---- h-part MFMAs: A-frag = h[m = lane&15][k = 32s + quad*8 + j] ----
#pragma unroll
      for (int s = 0; s < 16; ++s) {
        uint4_ d = *(const uint4_*)&hs[lm * 260 + s * 16 + quad * 4];
        union { uint4_ q; short8 v; } u; u.q = d;
        if (s & 1)
          acc2 = __builtin_amdgcn_mfma_f32_16x16x32_bf16(u.v, wh[s], acc2, 0, 0, 0);
        else
          acc = __builtin_amdgcn_mfma_f32_16x16x32_bf16(u.v, wh[s], acc, 0, 0, 0);
      }
    }

    // ---- pair z / h~ tiles via LDS (C/D: row = quad*4+r, col = lane&15) ----
    S[is_h][quad * 4 + 0][tile * 16 + lm] = acc[0] + acc2[0];
    S[is_h][quad * 4 + 1][tile * 16 + lm] = acc[1] + acc2[1];
    S[is_h][quad * 4 + 2][tile * 16 + lm] = acc[2] + acc2[2];
    S[is_h][quad * 4 + 3][tile * 16 + lm] = acc[3] + acc2[3];
    __syncthreads();

    // ---- epilogue: gates in fp32, update register-resident h ----
    float sz0 = S[0][em][ec]     + bz0;
    float sz1 = S[0][em][ec + 1] + bz1;
    float sh0 = S[1][em][ec]     + bh0;
    float sh1 = S[1][em][ec + 1] + bh1;
    float z0 = 1.f / (1.f + __expf(-sz0));
    float z1 = 1.f / (1.f + __expf(-sz1));
    float g0 = 1.f - 2.f / (1.f + __expf(2.f * sh0));
    float g1 = 1.f - 2.f / (1.f + __expf(2.f * sh1));
    hp0 += z0 * (g0 - hp0);
    hp1 += z1 * (g1 - hp1);

    // ---- publish h_t to slot t&3: fire and forget (no ACK, no flag) ----
    uint32_t pk = (uint32_t)f2bf(hp0) | ((uint32_t)f2bf(hp1) << 16);
    __hip_atomic_store(hbuf + (size_t)(t & 3) * HB_PAR + epair, pk,
                       __ATOMIC_RELAXED, __HIP_MEMORY_SCOPE_AGENT);

    // ---- output stores: off the critical path ----
    float2 ov; ov.x = hp0; ov.y = hp1;
    *(float2*)(outp + (size_t)t * Hh) = ov;
    if (t == Tt - 1)
      *(float2*)(out + (size_t)Bb * Tt * Hh + (size_t)eb * Hh + ecolg) = ov;
  }
}

extern "C" void kernel_launch(void* const* d_in, const int* in_sizes, int n_in,
                              void* d_out, int out_size, void* d_ws, size_t ws_size,
                              hipStream_t stream) {
  const float* x  = (const float*)d_in[0];
  const float* Wz = (const float*)d_in[1];
  const float* bz = (const float*)d_in[2];
  const float* Wh = (const float*)d_in[3];
  const float* bh = (const float*)d_in[4];
  float* out = (float*)d_out;
  uint32_t* hbuf = (uint32_t*)d_ws;  // 4 slots x 128 KB = 512 KB

  prep_kernel<<<dim3((NSLOT * HB_PAR + 255) / 256), dim3(256), 0, stream>>>(hbuf);
  mingru_kernel<<<dim3(64), dim3(512), 0, stream>>>(x, Wz, bz, Wh, bh, out, hbuf);
}